// Round 10
// baseline (1087.186 us; speedup 1.0000x reference)
//
#include <hip/hip_runtime.h>

#define N_USERS  100000
#define N_ITEMS  100000
#define N_NODES  200000
#define EMBED    64
#define NB       3
#define N_EDGESC 2000000
#define NE_TOT   (NB * N_EDGESC)     // 6M
#define BATCH    4096
#define M_SEG    (NB * N_NODES)      // 600000 flat segments
#define PSIZE    400                 // scan bucket width
#define NBUCK    (M_SEG / PSIZE)     // 1500
#define NE4      (N_EDGESC / 4)      // 500000 (exact)
#define SBLK     ((NE4 + 255) / 256) // 1954 blocks per behavior
#define GEMM_BLOCKS 3125             // 3125 blocks * 4 waves * 16 rows = 200000 exact
#define AGG_BLOCKS 6250              // 6250 * 32 nodes/block = 200000 exact
#define BPR_BLOCKS 1024
#define NPARTS   (GEMM_BLOCKS + NB * 1024)   // 3125 reg + 3072 bpr

typedef unsigned short u16;
typedef __attribute__((ext_vector_type(8))) short short8;   // 8 bf16 (4 VGPRs)
typedef __attribute__((ext_vector_type(4))) float f32x4;    // MFMA acc

__device__ __forceinline__ float b2f(u16 h) {
    return __uint_as_float(((unsigned)h) << 16);
}
__device__ __forceinline__ u16 f2b(float f) {
    unsigned u = __float_as_uint(f);
    return (u16)((u + 0x7FFF + ((u >> 16) & 1)) >> 16);   // RNE
}

// ---------------------------------------------------------------- degcount: per-node degree via global atomics
__global__ __launch_bounds__(256) void degcount(const int* __restrict__ edges,
                                                int* __restrict__ deg) {
    int bi  = blockIdx.x / SBLK;
    int blk = blockIdx.x - bi * SBLK;
    const int4* cols4 = (const int4*)(edges + ((size_t)bi * 2 + 1) * N_EDGESC);
    int i4 = blk * 256 + threadIdx.x;
    if (i4 < NE4) {
        int4 c = cols4[i4];
        int base = bi * N_NODES;
        atomicAdd(&deg[base + c.x], 1);
        atomicAdd(&deg[base + c.y], 1);
        atomicAdd(&deg[base + c.z], 1);
        atomicAdd(&deg[base + c.w], 1);
    }
}

// ---------------------------------------------------------------- bucket_sums: bCnt[b] = sum deg[b*400 .. +400)
__global__ __launch_bounds__(256) void bucket_sums(const int* __restrict__ deg,
                                                   int* __restrict__ bCnt) {
    __shared__ int ws[4];
    int b = blockIdx.x, t = threadIdx.x;
    int i0 = t * 2;
    int s = 0;
    if (i0     < PSIZE) s += deg[b * PSIZE + i0];
    if (i0 + 1 < PSIZE) s += deg[b * PSIZE + i0 + 1];
#pragma unroll
    for (int off = 32; off; off >>= 1) s += __shfl_xor(s, off, 64);
    if ((t & 63) == 0) ws[t >> 6] = s;
    __syncthreads();
    if (t == 0) bCnt[b] = ws[0] + ws[1] + ws[2] + ws[3];
}

// ---------------------------------------------------------------- scan NBUCK buckets (parallel)
__global__ __launch_bounds__(256) void scan_buckets(const int* __restrict__ bCnt,
                                                    int* __restrict__ bBase,
                                                    int* __restrict__ startv) {
    __shared__ int s[NBUCK + 1];
    __shared__ int tsum[256];
    int t = threadIdx.x;
    const int IT = (NBUCK + 255) / 256;     // 6
    int base0 = t * IT;
    int vals[IT];
    int sum = 0;
#pragma unroll
    for (int k = 0; k < IT; ++k) {
        int i = base0 + k;
        vals[k] = (i < NBUCK) ? bCnt[i] : 0;
        sum += vals[k];
    }
    tsum[t] = sum;
    __syncthreads();
    for (int off = 1; off < 256; off <<= 1) {
        int v = (t >= off) ? tsum[t - off] : 0;
        __syncthreads();
        tsum[t] += v;
        __syncthreads();
    }
    int run = tsum[t] - sum;
#pragma unroll
    for (int k = 0; k < IT; ++k) {
        int i = base0 + k;
        if (i < NBUCK) s[i] = run;
        run += vals[k];
    }
    if (t == 255) {
        s[NBUCK] = run;
        startv[M_SEG] = run;                // sentinel (= NE_TOT)
    }
    __syncthreads();
    for (int i = t; i < NBUCK + 1; i += 256) bBase[i] = s[i];
}

// ---------------------------------------------------------------- finalize: per-bucket scan of deg -> startv, cursor, dinv
__global__ __launch_bounds__(256) void finalize(const int* __restrict__ deg,
                                                const int* __restrict__ bBase,
                                                int* __restrict__ startv,
                                                int* __restrict__ cursor,
                                                float* __restrict__ dinv) {
    __shared__ int tsum[256];
    int b = blockIdx.x, t = threadIdx.x;
    int base = b * PSIZE;
    int i0 = t * 2;
    int v0 = (i0     < PSIZE) ? deg[base + i0]     : 0;
    int v1 = (i0 + 1 < PSIZE) ? deg[base + i0 + 1] : 0;
    int sum = v0 + v1;
    tsum[t] = sum;
    __syncthreads();
    for (int off = 1; off < 256; off <<= 1) {
        int v = (t >= off) ? tsum[t - off] : 0;
        __syncthreads();
        tsum[t] += v;
        __syncthreads();
    }
    int run = tsum[t] - sum;    // exclusive within bucket
    int gb  = bBase[b];
    if (i0 < PSIZE) {
        int sv = gb + run;
        startv[base + i0] = sv;
        cursor[base + i0] = sv;
        dinv[base + i0]   = (v0 > 0) ? rsqrtf((float)v0) : 0.0f;
    }
    if (i0 + 1 < PSIZE) {
        int sv = gb + run + v0;
        startv[base + i0 + 1] = sv;
        cursor[base + i0 + 1] = sv;
        dinv[base + i0 + 1]   = (v1 > 0) ? rsqrtf((float)v1) : 0.0f;
    }
}

// ---------------------------------------------------------------- scatter_direct: srow[atomic cursor] = row
// Within-node order is atomic-arrival order (nondeterministic); only permutes
// an f32 summation of ~deg terms in agg (~1e-7 rel), far below bf16 noise.
__global__ __launch_bounds__(256) void scatter_direct(const int* __restrict__ edges,
                                                      int* __restrict__ cursor,
                                                      int* __restrict__ srow) {
    int bi  = blockIdx.x / SBLK;
    int blk = blockIdx.x - bi * SBLK;
    const int4* rows4 = (const int4*)(edges + ((size_t)bi * 2 + 0) * N_EDGESC);
    const int4* cols4 = (const int4*)(edges + ((size_t)bi * 2 + 1) * N_EDGESC);
    int i4 = blk * 256 + threadIdx.x;
    if (i4 < NE4) {
        int4 c = cols4[i4];
        int4 r = rows4[i4];
        int base = bi * N_NODES;
        int p0 = atomicAdd(&cursor[base + c.x], 1);
        int p1 = atomicAdd(&cursor[base + c.y], 1);
        int p2 = atomicAdd(&cursor[base + c.z], 1);
        int p3 = atomicAdd(&cursor[base + c.w], 1);
        srow[p0] = r.x;
        srow[p1] = r.y;
        srow[p2] = r.z;
        srow[p3] = r.w;
    }
}

// ---------------------------------------------------------------- B-fragment loader: Bf[ct][kt] = bf16 W[k][ct*16+n]
// layout per m120: B[k = quad*8 + j][n = lane&15]
__device__ __forceinline__ void load_Bfrag(const float* __restrict__ W,
                                           int lane, short8 Bf[4][2]) {
    int n    = lane & 15;
    int kb   = (lane >> 4) * 8;
#pragma unroll
    for (int ct = 0; ct < 4; ++ct)
#pragma unroll
        for (int kt = 0; kt < 2; ++kt)
#pragma unroll
            for (int j = 0; j < 8; ++j)
                Bf[ct][kt][j] = (short)f2b(W[(kt * 32 + kb + j) * 64 + ct * 16 + n]);
}

// ---------------------------------------------------------------- MFMA store, pre-scaled by dinv[src]:
// x16[r] = bf16( dinv[base+r] * (X @ W)[r] )  -- agg then needs no per-edge dinv gather.
// C/D layout: col=lane&15, row=quad*4+reg
__device__ __forceinline__ void store_tile(u16* __restrict__ x16,
                                           const float* __restrict__ dinv, int base,
                                           int r0, int lane, const f32x4 acc[4]) {
    int col  = lane & 15;
    int rowb = (lane >> 4) * 4;
    float dv[4];
#pragma unroll
    for (int j = 0; j < 4; ++j) dv[j] = dinv[base + r0 + rowb + j];
#pragma unroll
    for (int ct = 0; ct < 4; ++ct)
#pragma unroll
        for (int j = 0; j < 4; ++j)
            x16[(size_t)(r0 + rowb + j) * 64 + ct * 16 + col] = f2b(acc[ct][j] * dv[j]);
}

// ---------------------------------------------------------------- mfma_first: x16 = bf16(dinv * concat(ue,ie) @ W0), fused reg loss
__global__ __launch_bounds__(256) void mfma_first(const float* __restrict__ ue,
                                                  const float* __restrict__ ie,
                                                  const float* __restrict__ W,
                                                  const float* __restrict__ dinv,
                                                  u16* __restrict__ x16,
                                                  float* __restrict__ regpart) {
    __shared__ float wsum[4];
    int lane = threadIdx.x & 63;
    short8 Bf[4][2];
    load_Bfrag(W, lane, Bf);

    int r0 = (blockIdx.x * 4 + (threadIdx.x >> 6)) * 16;
    int m  = lane & 15;
    int kb = (lane >> 4) * 8;
    int r  = r0 + m;
    const float* src = (r < N_USERS) ? (ue + (size_t)r * 64)
                                     : (ie + (size_t)(r - N_USERS) * 64);
    // A fragments: A[m][k=kb+j] (kt0), A[m][32+kb+j] (kt1); 8 f32 -> short8 each
    float sq = 0.0f;
    short8 A0, A1;
#pragma unroll
    for (int h = 0; h < 2; ++h) {
        float4 a = ((const float4*)(src + h * 32 + kb))[0];
        float4 b = ((const float4*)(src + h * 32 + kb))[1];
        short8& A = h ? A1 : A0;
        A[0] = (short)f2b(a.x); A[1] = (short)f2b(a.y);
        A[2] = (short)f2b(a.z); A[3] = (short)f2b(a.w);
        A[4] = (short)f2b(b.x); A[5] = (short)f2b(b.y);
        A[6] = (short)f2b(b.z); A[7] = (short)f2b(b.w);
        sq += a.x * a.x + a.y * a.y + a.z * a.z + a.w * a.w;
        sq += b.x * b.x + b.y * b.y + b.z * b.z + b.w * b.w;
    }
    f32x4 acc[4];
#pragma unroll
    for (int ct = 0; ct < 4; ++ct) {
        acc[ct] = (f32x4){0.f, 0.f, 0.f, 0.f};
        acc[ct] = __builtin_amdgcn_mfma_f32_16x16x32_bf16(A0, Bf[ct][0], acc[ct], 0, 0, 0);
        acc[ct] = __builtin_amdgcn_mfma_f32_16x16x32_bf16(A1, Bf[ct][1], acc[ct], 0, 0, 0);
    }
    store_tile(x16, dinv, 0, r0, lane, acc);

#pragma unroll
    for (int off = 32; off; off >>= 1) sq += __shfl_xor(sq, off, 64);
    if (lane == 0) wsum[threadIdx.x >> 6] = sq;
    __syncthreads();
    if (threadIdx.x == 0)
        regpart[blockIdx.x] = (wsum[0] + wsum[1] + wsum[2] + wsum[3]) *
                              (0.5f * 0.0001f / (float)BATCH);
}

// ---------------------------------------------------------------- fused: mfma_gemm (layer bi+1) + bpr (layer bi)
// Both roles only READ g16 (the completed layer-bi output) -> safe in one grid.
__global__ __launch_bounds__(256) void gemm_bpr(const u16* __restrict__ g16,
                                                const float* __restrict__ W,
                                                const float* __restrict__ dinv,
                                                int base,
                                                u16* __restrict__ x16,
                                                const int* __restrict__ batch,
                                                int bi,
                                                float* __restrict__ bprpart) {
    __shared__ float sp4[4];
    if (blockIdx.x < GEMM_BLOCKS) {
        int lane = threadIdx.x & 63;
        short8 Bf[4][2];
        load_Bfrag(W, lane, Bf);

        int r0 = (blockIdx.x * 4 + (threadIdx.x >> 6)) * 16;
        int m  = lane & 15;
        int kb = (lane >> 4) * 8;
        const u16* src = g16 + (size_t)(r0 + m) * 64 + kb;
        short8 A0 = *(const short8*)(src);
        short8 A1 = *(const short8*)(src + 32);
        f32x4 acc[4];
#pragma unroll
        for (int ct = 0; ct < 4; ++ct) {
            acc[ct] = (f32x4){0.f, 0.f, 0.f, 0.f};
            acc[ct] = __builtin_amdgcn_mfma_f32_16x16x32_bf16(A0, Bf[ct][0], acc[ct], 0, 0, 0);
            acc[ct] = __builtin_amdgcn_mfma_f32_16x16x32_bf16(A1, Bf[ct][1], acc[ct], 0, 0, 0);
        }
        store_tile(x16, dinv, base, r0, lane, acc);
    } else {
        int blk  = blockIdx.x - GEMM_BLOCKS;
        int b    = blk * 4 + (threadIdx.x >> 6);
        int lane = threadIdx.x & 63;
        int u  = batch[((size_t)b * NB + bi) * 3 + 0];
        int i0 = batch[((size_t)b * NB + bi) * 3 + 1];
        int i1 = batch[((size_t)b * NB + bi) * 3 + 2];
        float uf = b2f(g16[(size_t)u * 64 + lane]);
        float f0 = b2f(g16[(size_t)(N_USERS + i0) * 64 + lane]);
        float f1 = b2f(g16[(size_t)(N_USERS + i1) * 64 + lane]);
        float d  = uf * (f0 - f1);
#pragma unroll
        for (int off = 32; off; off >>= 1) d += __shfl_xor(d, off, 64);
        float sp = (d > 0.0f) ? log1pf(expf(-d)) : (-d + log1pf(expf(d)));
        if (lane == 0) sp4[threadIdx.x >> 6] = sp;
        __syncthreads();
        if (threadIdx.x == 0)
            bprpart[blk] = (sp4[0] + sp4[1] + sp4[2] + sp4[3]) * (1.0f / BATCH);
    }
}

// ---------------------------------------------------------------- agg: gather-sum + bias + l2norm + residual
// 8 nodes/wave (one per 8-lane subgroup, 8 dims/lane, 16 B row loads).
// Steady loop software-pipelined: next batch's srow indices prefetched before
// the current batch's row gathers (breaks the srow->xv dependent chain).
__global__ __launch_bounds__(256) void agg_kernel(const int* __restrict__ srow,
                                                  const int* __restrict__ startv,
                                                  const float* __restrict__ dinv,
                                                  const int4* __restrict__ xv,
                                                  const float4* __restrict__ reslo,
                                                  const float4* __restrict__ reshi,
                                                  const int4* __restrict__ res16,
                                                  int resf32,
                                                  int4* __restrict__ g16out,
                                                  const float* __restrict__ bias,
                                                  int base /* bi*N_NODES */) {
    int lane = threadIdx.x & 63;
    int li   = lane & 7;                                        // dim chunk (8 dims, 16 B)
    int c = (blockIdx.x * 4 + (threadIdx.x >> 6)) * 8 + (lane >> 3);  // < 200000 exact

    int   s   = startv[base + c];
    int   end = startv[base + c + 1];
    float dc  = dinv[base + c];

    float acc[8];
#pragma unroll
    for (int d = 0; d < 8; ++d) acc[d] = 0.0f;

    int e = s;
    // steady state: full 8-edge batches, srow prefetched one batch ahead
    if (e + 8 <= end) {
        int r[8];
#pragma unroll
        for (int j = 0; j < 8; ++j) r[j] = srow[e + j];
        for (;;) {
            int  e2    = e + 8;
            bool have2 = (e2 + 8 <= end);
            int  rn[8];
            if (have2) {
#pragma unroll
                for (int j = 0; j < 8; ++j) rn[j] = srow[e2 + j];
            }
#pragma unroll
            for (int jj = 0; jj < 8; ++jj) {
                int4 w = xv[(size_t)r[jj] * 8 + li];
                acc[0] += __uint_as_float(((unsigned)w.x) << 16);
                acc[1] += __uint_as_float(((unsigned)w.x) & 0xFFFF0000u);
                acc[2] += __uint_as_float(((unsigned)w.y) << 16);
                acc[3] += __uint_as_float(((unsigned)w.y) & 0xFFFF0000u);
                acc[4] += __uint_as_float(((unsigned)w.z) << 16);
                acc[5] += __uint_as_float(((unsigned)w.z) & 0xFFFF0000u);
                acc[6] += __uint_as_float(((unsigned)w.w) << 16);
                acc[7] += __uint_as_float(((unsigned)w.w) & 0xFFFF0000u);
            }
            e = e2;
            if (!have2) break;
#pragma unroll
            for (int j = 0; j < 8; ++j) r[j] = rn[j];
        }
    }
    // tail: masked via exact 0/1 fma multiplier
    if (e < end) {
#pragma unroll
        for (int jj = 0; jj < 8; ++jj) {
            int  ej = e + jj;
            bool ok = ej < end;
            int  ec = ok ? ej : s;
            int  r  = srow[ec];
            int4 w  = xv[(size_t)r * 8 + li];
            float m = ok ? 1.0f : 0.0f;
            acc[0] += m * __uint_as_float(((unsigned)w.x) << 16);
            acc[1] += m * __uint_as_float(((unsigned)w.x) & 0xFFFF0000u);
            acc[2] += m * __uint_as_float(((unsigned)w.y) << 16);
            acc[3] += m * __uint_as_float(((unsigned)w.y) & 0xFFFF0000u);
            acc[4] += m * __uint_as_float(((unsigned)w.z) << 16);
            acc[5] += m * __uint_as_float(((unsigned)w.z) & 0xFFFF0000u);
            acc[6] += m * __uint_as_float(((unsigned)w.w) << 16);
            acc[7] += m * __uint_as_float(((unsigned)w.w) & 0xFFFF0000u);
        }
    }

    float4 b0 = ((const float4*)bias)[li * 2];
    float4 b1 = ((const float4*)bias)[li * 2 + 1];
    float v[8];
    v[0] = acc[0] * dc + b0.x; v[1] = acc[1] * dc + b0.y;
    v[2] = acc[2] * dc + b0.z; v[3] = acc[3] * dc + b0.w;
    v[4] = acc[4] * dc + b1.x; v[5] = acc[5] * dc + b1.y;
    v[6] = acc[6] * dc + b1.z; v[7] = acc[7] * dc + b1.w;
    float sq = 0.0f;
#pragma unroll
    for (int d = 0; d < 8; ++d) sq += v[d] * v[d];
    sq += __shfl_xor(sq, 1, 64);
    sq += __shfl_xor(sq, 2, 64);
    sq += __shfl_xor(sq, 4, 64);
    float inv = 1.0f / fmaxf(sqrtf(sq), 1e-12f);

    float rv[8];
    if (resf32) {
        const float4* rsrc = (c < N_USERS)
            ? reslo + ((size_t)c * 16 + li * 2)
            : reshi + ((size_t)(c - N_USERS) * 16 + li * 2);
        float4 t0 = rsrc[0], t1 = rsrc[1];
        rv[0] = t0.x; rv[1] = t0.y; rv[2] = t0.z; rv[3] = t0.w;
        rv[4] = t1.x; rv[5] = t1.y; rv[6] = t1.z; rv[7] = t1.w;
    } else {
        int4 rw = res16[(size_t)c * 8 + li];
        rv[0] = __uint_as_float(((unsigned)rw.x) << 16);
        rv[1] = __uint_as_float(((unsigned)rw.x) & 0xFFFF0000u);
        rv[2] = __uint_as_float(((unsigned)rw.y) << 16);
        rv[3] = __uint_as_float(((unsigned)rw.y) & 0xFFFF0000u);
        rv[4] = __uint_as_float(((unsigned)rw.z) << 16);
        rv[5] = __uint_as_float(((unsigned)rw.z) & 0xFFFF0000u);
        rv[6] = __uint_as_float(((unsigned)rw.w) << 16);
        rv[7] = __uint_as_float(((unsigned)rw.w) & 0xFFFF0000u);
    }
    float o[8];
#pragma unroll
    for (int d = 0; d < 8; ++d) o[d] = rv[d] + v[d] * inv;
    int4 h;
    h.x = (int)(((unsigned)f2b(o[0])) | (((unsigned)f2b(o[1])) << 16));
    h.y = (int)(((unsigned)f2b(o[2])) | (((unsigned)f2b(o[3])) << 16));
    h.z = (int)(((unsigned)f2b(o[4])) | (((unsigned)f2b(o[5])) << 16));
    h.w = (int)(((unsigned)f2b(o[6])) | (((unsigned)f2b(o[7])) << 16));
    g16out[(size_t)c * 8 + li] = h;
}

// ---------------------------------------------------------------- BPR loss standalone (last layer) — bf16 rows
__global__ __launch_bounds__(256) void bpr_kernel(const u16* __restrict__ g16,
                                                  const int* __restrict__ batch,
                                                  int bi, float* __restrict__ bprpart) {
    __shared__ float sp4[4];
    int b    = blockIdx.x * 4 + (threadIdx.x >> 6);   // 1024 blocks, 4 samples each
    int lane = threadIdx.x & 63;
    int u  = batch[((size_t)b * NB + bi) * 3 + 0];
    int i0 = batch[((size_t)b * NB + bi) * 3 + 1];
    int i1 = batch[((size_t)b * NB + bi) * 3 + 2];
    float uf = b2f(g16[(size_t)u * 64 + lane]);
    float f0 = b2f(g16[(size_t)(N_USERS + i0) * 64 + lane]);
    float f1 = b2f(g16[(size_t)(N_USERS + i1) * 64 + lane]);
    float d  = uf * (f0 - f1);
#pragma unroll
    for (int off = 32; off; off >>= 1) d += __shfl_xor(d, off, 64);
    float sp = (d > 0.0f) ? log1pf(expf(-d)) : (-d + log1pf(expf(d)));
    if (lane == 0) sp4[threadIdx.x >> 6] = sp;
    __syncthreads();
    if (threadIdx.x == 0)
        bprpart[blockIdx.x] = (sp4[0] + sp4[1] + sp4[2] + sp4[3]) * (1.0f / BATCH);
}

// ---------------------------------------------------------------- final: reduce all partials
__global__ __launch_bounds__(256) void final_write(const float* __restrict__ parts,
                                                   float* __restrict__ out) {
    __shared__ float ws[4];
    float s = 0.0f;
    for (int i = threadIdx.x; i < NPARTS; i += 256) s += parts[i];
#pragma unroll
    for (int off = 32; off; off >>= 1) s += __shfl_xor(s, off, 64);
    if ((threadIdx.x & 63) == 0) ws[threadIdx.x >> 6] = s;
    __syncthreads();
    if (threadIdx.x == 0) out[0] = ws[0] + ws[1] + ws[2] + ws[3];
}

extern "C" void kernel_launch(void* const* d_in, const int* in_sizes, int n_in,
                              void* d_out, int out_size, void* d_ws, size_t ws_size,
                              hipStream_t stream) {
    const float* user_emb = (const float*)d_in[0];
    const float* item_emb = (const float*)d_in[1];
    const float* gcn_w    = (const float*)d_in[2];
    const float* gcn_b    = (const float*)d_in[3];
    const int*   edges    = (const int*)d_in[4];
    const int*   batch    = (const int*)d_in[5];
    float*       out      = (float*)d_out;

    const size_t NODE_F = (size_t)N_NODES * EMBED;            // 12.8M elems
    u16*     g16A   = (u16*)d_ws;                             // 25.6 MB bf16 master A
    u16*     g16B   = g16A + NODE_F;                          // 25.6 MB bf16 master B
    u16*     x16    = g16B + NODE_F;                          // 25.6 MB bf16 gemm out (dinv-prescaled)
    float*   dinv   = (float*)(x16 + NODE_F);                 //  2.4 MB
    int*     startv = (int*)(dinv + M_SEG);                   //  2.4 MB (+1 sentinel)
    int*     deg    = startv + M_SEG + 1;                     //  2.4 MB
    int*     cursor = deg + M_SEG;                            //  2.4 MB
    int*     bCnt   = cursor + M_SEG;                         //  6 KB
    int*     bBase  = bCnt + NBUCK;                           //  6 KB
    int*     srow   = bBase + NBUCK + 1;                      //  24 MB
    float*   parts  = (float*)(srow + NE_TOT);                //  25 KB partials
    float*   regpart = parts;                                 //  [0, 3125)
    float*   bprpart = parts + GEMM_BLOCKS;                   //  [3125, 3125+3072)

    // direct CSR build: degree count -> scan -> atomic scatter (no bpack roundtrip)
    hipMemsetAsync(deg, 0, (size_t)M_SEG * sizeof(int), stream);
    degcount<<<NB * SBLK, 256, 0, stream>>>(edges, deg);
    bucket_sums<<<NBUCK, 256, 0, stream>>>(deg, bCnt);
    scan_buckets<<<1, 256, 0, stream>>>(bCnt, bBase, startv);
    finalize<<<NBUCK, 256, 0, stream>>>(deg, bBase, startv, cursor, dinv);
    scatter_direct<<<NB * SBLK, 256, 0, stream>>>(edges, cursor, srow);

    // layer-0 GEMM via MFMA: reads restore-warm f32 inputs; fuses reg loss
    mfma_first<<<GEMM_BLOCKS, 256, 0, stream>>>(user_emb, item_emb,
                                                gcn_w, dinv, x16, regpart);

    // layer 0: f32 residual (original inputs), bf16 output master
    agg_kernel<<<AGG_BLOCKS, 256, 0, stream>>>(
        srow, startv, dinv, (const int4*)x16,
        (const float4*)user_emb, (const float4*)item_emb,
        (const int4*)0, 1,
        (int4*)g16A, gcn_b, 0);

    // layers 1, 2: bf16 residual chain; gemm(bi) fused with bpr(bi-1)
    u16* gcur = g16A;
    u16* gnxt = g16B;
    for (int bi = 1; bi < NB; ++bi) {
        gemm_bpr<<<GEMM_BLOCKS + BPR_BLOCKS, 256, 0, stream>>>(
            gcur, gcn_w + (size_t)bi * EMBED * EMBED, dinv, bi * N_NODES, x16,
            batch, bi - 1, bprpart + (size_t)(bi - 1) * BPR_BLOCKS);
        agg_kernel<<<AGG_BLOCKS, 256, 0, stream>>>(
            srow, startv, dinv, (const int4*)x16,
            (const float4*)0, (const float4*)0,
            (const int4*)gcur, 0,
            (int4*)gnxt, gcn_b + bi * EMBED, bi * N_NODES);
        u16* tmp = gcur; gcur = gnxt; gnxt = tmp;
    }
    // last layer's bpr (reads gcur = output of agg layer 2)
    bpr_kernel<<<BPR_BLOCKS, 256, 0, stream>>>(gcur, batch, NB - 1,
                                               bprpart + (size_t)(NB - 1) * BPR_BLOCKS);
    final_write<<<1, 256, 0, stream>>>(parts, out);
}

// Round 11
// 365.920 us; speedup vs baseline: 2.9711x; 2.9711x over previous
//
#include <hip/hip_runtime.h>

#define N_USERS  100000
#define N_ITEMS  100000
#define N_NODES  200000
#define EMBED    64
#define NB       3
#define N_EDGESC 2000000
#define NE_TOT   (NB * N_EDGESC)     // 6M
#define BATCH    4096
#define M_SEG    (NB * N_NODES)      // 600000 flat segments
#define NPART    500
#define PSIZE    400                 // N_NODES / NPART (exact)
#define NBUCK    (NB * NPART)        // 1500
#define NBLKB    256                 // edge blocks per behavior (8192 edges each)
#define EPB      8192
#define EPB4     (EPB / 4)           // 2048 int4 per block
#define NE4      (N_EDGESC / 4)      // 500000 (exact)
#define STAGE_CAP 4416               // bucket mean 4000, +6.5 sigma; LDS-staged srow
#define GEMM_BLOCKS 3125             // 3125 blocks * 4 waves * 16 rows = 200000 exact
#define AGG_BLOCKS 6250              // 6250 * 32 nodes/block = 200000 exact
#define BPR_BLOCKS 1024
#define NPARTS   (GEMM_BLOCKS + NB * 1024)   // 3125 reg + 3072 bpr

typedef unsigned short u16;
typedef __attribute__((ext_vector_type(8))) short short8;   // 8 bf16 (4 VGPRs)
typedef __attribute__((ext_vector_type(4))) float f32x4;    // MFMA acc

__device__ __forceinline__ float b2f(u16 h) {
    return __uint_as_float(((unsigned)h) << 16);
}
__device__ __forceinline__ u16 f2b(float f) {
    unsigned u = __float_as_uint(f);
    return (u16)((u + 0x7FFF + ((u >> 16) & 1)) >> 16);   // RNE
}

// ---------------------------------------------------------------- scatterA: per-(bucket,block) hist (int4 reads)
__global__ __launch_bounds__(256) void scatterA(const int* __restrict__ edges,
                                                int* __restrict__ H) {
    __shared__ int h[NPART];
    int bi  = blockIdx.x / NBLKB;
    int blk = blockIdx.x - bi * NBLKB;
    const int4* cols4 = (const int4*)(edges + ((size_t)bi * 2 + 1) * N_EDGESC);
    for (int i = threadIdx.x; i < NPART; i += 256) h[i] = 0;
    __syncthreads();
    int b4 = blk * EPB4;
#pragma unroll 2
    for (int it = 0; it < EPB4 / 256; ++it) {
        int i4 = b4 + it * 256 + threadIdx.x;
        if (i4 < NE4) {
            int4 c = cols4[i4];
            atomicAdd(&h[c.x / PSIZE], 1);
            atomicAdd(&h[c.y / PSIZE], 1);
            atomicAdd(&h[c.z / PSIZE], 1);
            atomicAdd(&h[c.w / PSIZE], 1);
        }
    }
    __syncthreads();
    for (int i = threadIdx.x; i < NPART; i += 256)
        H[(bi * NPART + i) * NBLKB + blk] = h[i];
}

// ---------------------------------------------------------------- colscan: per-bucket exclusive scan over NBLKB=256 blocks
__global__ __launch_bounds__(256) void colscan(int* __restrict__ H,
                                               int* __restrict__ bCnt) {
    int wid = blockIdx.x * 4 + (threadIdx.x >> 6);
    if (wid >= NBUCK) return;
    int lane = threadIdx.x & 63;
    int carry = 0;
#pragma unroll
    for (int ch = 0; ch < NBLKB / 64; ++ch) {
        int i = wid * NBLKB + ch * 64 + lane;
        int v = H[i];
        int s = v;
#pragma unroll
        for (int off = 1; off < 64; off <<= 1) {
            int tt = __shfl_up(s, off, 64);
            if (lane >= off) s += tt;
        }
        H[i] = carry + s - v;
        carry += __shfl(s, 63, 64);
    }
    if (lane == 0) bCnt[wid] = carry;
}

// ---------------------------------------------------------------- scan NBUCK buckets (parallel)
__global__ __launch_bounds__(256) void scan_buckets(const int* __restrict__ bCnt,
                                                    int* __restrict__ bBase,
                                                    int* __restrict__ startv) {
    __shared__ int s[NBUCK + 1];
    __shared__ int tsum[256];
    int t = threadIdx.x;
    const int IT = (NBUCK + 255) / 256;     // 6
    int base0 = t * IT;
    int vals[IT];
    int sum = 0;
#pragma unroll
    for (int k = 0; k < IT; ++k) {
        int i = base0 + k;
        vals[k] = (i < NBUCK) ? bCnt[i] : 0;
        sum += vals[k];
    }
    tsum[t] = sum;
    __syncthreads();
    for (int off = 1; off < 256; off <<= 1) {
        int v = (t >= off) ? tsum[t - off] : 0;
        __syncthreads();
        tsum[t] += v;
        __syncthreads();
    }
    int run = tsum[t] - sum;
#pragma unroll
    for (int k = 0; k < IT; ++k) {
        int i = base0 + k;
        if (i < NBUCK) s[i] = run;
        run += vals[k];
    }
    if (t == 255) {
        s[NBUCK] = run;
        startv[M_SEG] = run;                // sentinel
    }
    __syncthreads();
    for (int i = t; i < NBUCK + 1; i += 256) bBase[i] = s[i];
}

// ---------------------------------------------------------------- scatterB: bucket placement, counts derived from scanned H.
// int4 edge reads; single pass: cursor atomics -> 32KB LDS stage -> run dump.
__global__ __launch_bounds__(256) void scatterB(const int* __restrict__ edges,
                                                const int* __restrict__ H,
                                                const int* __restrict__ bCnt,
                                                const int* __restrict__ bBase,
                                                int* __restrict__ bpack) {
    __shared__ int cur[NPART + 2];      // counts -> exclusive scan -> cursor
    __shared__ int lstart[NPART + 1];   // local exclusive scan (kept for dump)
    __shared__ int sbase[NPART];        // global base for (bucket, this block)
    __shared__ int tsum[256];
    __shared__ int stage[EPB];          // 32 KB bucket-sorted packed edges
    int bi  = blockIdx.x / NBLKB;
    int blk = blockIdx.x - bi * NBLKB;
    const int4* rows4 = (const int4*)(edges + ((size_t)bi * 2 + 0) * N_EDGESC);
    const int4* cols4 = (const int4*)(edges + ((size_t)bi * 2 + 1) * N_EDGESC);
    int t = threadIdx.x;

    // per-bucket count for this block from scanned H: cnt = H[blk+1]-H[blk]
    for (int i = t; i < NPART; i += 256) {
        int b  = bi * NPART + i;
        int hc = H[b * NBLKB + blk];
        int nx = (blk < NBLKB - 1) ? H[b * NBLKB + blk + 1] : bCnt[b];
        sbase[i] = bBase[b] + hc;
        cur[i]   = nx - hc;
    }
    if (t == 0) cur[NPART] = 0;
    __syncthreads();

    // scan cur[0..NPART] (2 items/thread covers 512 >= 501)
    int sb0 = t * 2;
    int v0 = (sb0     <= NPART) ? cur[sb0]     : 0;
    int v1 = (sb0 + 1 <= NPART) ? cur[sb0 + 1] : 0;
    int sum = v0 + v1;
    tsum[t] = sum;
    __syncthreads();
    for (int off = 1; off < 256; off <<= 1) {
        int v = (t >= off) ? tsum[t - off] : 0;
        __syncthreads();
        tsum[t] += v;
        __syncthreads();
    }
    int run = tsum[t] - sum;
    __syncthreads();
    if (sb0     <= NPART) { cur[sb0]     = run;      lstart[sb0]     = run; }
    if (sb0 + 1 <= NPART) { cur[sb0 + 1] = run + v0; lstart[sb0 + 1] = run + v0; }
    __syncthreads();

    // single main pass: int4 load (4 edges), rank via LDS cursor atomics, scatter
    int b4 = blk * EPB4;
#pragma unroll 2
    for (int it = 0; it < EPB4 / 256; ++it) {
        int i4 = b4 + it * 256 + t;
        if (i4 < NE4) {
            int4 c = cols4[i4];
            int4 r = rows4[i4];
            { int p = c.x / PSIZE; int q = atomicAdd(&cur[p], 1);
              stage[q] = ((c.x - p * PSIZE) << 18) | r.x; }
            { int p = c.y / PSIZE; int q = atomicAdd(&cur[p], 1);
              stage[q] = ((c.y - p * PSIZE) << 18) | r.y; }
            { int p = c.z / PSIZE; int q = atomicAdd(&cur[p], 1);
              stage[q] = ((c.z - p * PSIZE) << 18) | r.z; }
            { int p = c.w / PSIZE; int q = atomicAdd(&cur[p], 1);
              stage[q] = ((c.w - p * PSIZE) << 18) | r.w; }
        }
    }
    __syncthreads();

    // run-based dump: 16 lanes per bucket (runs avg ~16 words -> one 64B line)
    int grp = t >> 4;       // 16 groups of 16 lanes
    int li  = t & 15;
    for (int p = grp; p < NPART; p += 16) {
        int lb  = lstart[p];
        int len = lstart[p + 1] - lb;
        int gb  = sbase[p];
        for (int off = li; off < len; off += 16)
            bpack[gb + off] = stage[lb + off];
    }
}

// ---------------------------------------------------------------- place: one block per bucket
// hist -> scan -> startv/dinv -> rank-scatter into LDS stage -> coalesced srow dump.
__global__ __launch_bounds__(256) void place_kernel(const int* __restrict__ bpack,
                                                    const int* __restrict__ bBase,
                                                    int* __restrict__ startv,
                                                    float* __restrict__ dinv,
                                                    int* __restrict__ srow) {
    __shared__ int cnt[PSIZE + 2];
    __shared__ int tsum[256];
    __shared__ int stage[STAGE_CAP];
    int b    = blockIdx.x;
    int bi   = b / NPART;
    int part = b - bi * NPART;
    int segBase = bi * N_NODES + part * PSIZE;
    int lo = bBase[b], hiEnd = bBase[b + 1];
    int t = threadIdx.x;

    for (int i = t; i < PSIZE + 1; i += 256) cnt[i] = 0;
    __syncthreads();

    // phase 1: histogram (4-batched loads so 4 loads are in flight before atomics)
    {
        int i = lo + t;
        for (; i + 768 < hiEnd; i += 1024) {
            int a0 = bpack[i];
            int a1 = bpack[i + 256];
            int a2 = bpack[i + 512];
            int a3 = bpack[i + 768];
            atomicAdd(&cnt[a0 >> 18], 1);
            atomicAdd(&cnt[a1 >> 18], 1);
            atomicAdd(&cnt[a2 >> 18], 1);
            atomicAdd(&cnt[a3 >> 18], 1);
        }
        for (; i < hiEnd; i += 256) atomicAdd(&cnt[bpack[i] >> 18], 1);
    }
    __syncthreads();

    // scan cnt[0..PSIZE] (2 items/thread covers 512 >= 401)
    int base0 = t * 2;
    int v0 = (base0     <= PSIZE) ? cnt[base0]     : 0;
    int v1 = (base0 + 1 <= PSIZE) ? cnt[base0 + 1] : 0;
    int sum = v0 + v1;
    tsum[t] = sum;
    __syncthreads();
    for (int off = 1; off < 256; off <<= 1) {
        int v = (t >= off) ? tsum[t - off] : 0;
        __syncthreads();
        tsum[t] += v;
        __syncthreads();
    }
    int run = tsum[t] - sum;
    __syncthreads();
    if (base0     <= PSIZE) cnt[base0]     = run;
    if (base0 + 1 <= PSIZE) cnt[base0 + 1] = run + v0;
    __syncthreads();

    for (int i = t; i < PSIZE; i += 256) {
        int excl = cnt[i];
        int d    = cnt[i + 1] - excl;
        startv[segBase + i] = lo + excl;
        dinv[segBase + i]   = (d > 0) ? rsqrtf((float)d) : 0.0f;
    }
    __syncthreads();

    // phase 2: rank (LDS atomic) + stage into LDS; overflow falls back to direct write
    {
        int i = lo + t;
        for (; i + 768 < hiEnd; i += 1024) {
            int p0 = bpack[i];
            int p1 = bpack[i + 256];
            int p2 = bpack[i + 512];
            int p3 = bpack[i + 768];
            int q0 = atomicAdd(&cnt[p0 >> 18], 1);
            int q1 = atomicAdd(&cnt[p1 >> 18], 1);
            int q2 = atomicAdd(&cnt[p2 >> 18], 1);
            int q3 = atomicAdd(&cnt[p3 >> 18], 1);
            if (q0 < STAGE_CAP) stage[q0] = p0 & 0x3FFFF; else srow[lo + q0] = p0 & 0x3FFFF;
            if (q1 < STAGE_CAP) stage[q1] = p1 & 0x3FFFF; else srow[lo + q1] = p1 & 0x3FFFF;
            if (q2 < STAGE_CAP) stage[q2] = p2 & 0x3FFFF; else srow[lo + q2] = p2 & 0x3FFFF;
            if (q3 < STAGE_CAP) stage[q3] = p3 & 0x3FFFF; else srow[lo + q3] = p3 & 0x3FFFF;
        }
        for (; i < hiEnd; i += 256) {
            int pk  = bpack[i];
            int pos = atomicAdd(&cnt[pk >> 18], 1);
            if (pos < STAGE_CAP) stage[pos] = pk & 0x3FFFF; else srow[lo + pos] = pk & 0x3FFFF;
        }
    }
    __syncthreads();

    // coalesced dump
    int n = hiEnd - lo;
    int cap = (n < STAGE_CAP) ? n : STAGE_CAP;
    for (int i = t; i < cap; i += 256) srow[lo + i] = stage[i];
}

// ---------------------------------------------------------------- B-fragment loader: Bf[ct][kt] = bf16 W[k][ct*16+n]
// layout per m120: B[k = quad*8 + j][n = lane&15]
__device__ __forceinline__ void load_Bfrag(const float* __restrict__ W,
                                           int lane, short8 Bf[4][2]) {
    int n    = lane & 15;
    int kb   = (lane >> 4) * 8;
#pragma unroll
    for (int ct = 0; ct < 4; ++ct)
#pragma unroll
        for (int kt = 0; kt < 2; ++kt)
#pragma unroll
            for (int j = 0; j < 8; ++j)
                Bf[ct][kt][j] = (short)f2b(W[(kt * 32 + kb + j) * 64 + ct * 16 + n]);
}

// ---------------------------------------------------------------- MFMA store, pre-scaled by dinv[src]:
// x16[r] = bf16( dinv[base+r] * (X @ W)[r] )  -- agg then needs no per-edge dinv gather.
// C/D layout: col=lane&15, row=quad*4+reg
__device__ __forceinline__ void store_tile(u16* __restrict__ x16,
                                           const float* __restrict__ dinv, int base,
                                           int r0, int lane, const f32x4 acc[4]) {
    int col  = lane & 15;
    int rowb = (lane >> 4) * 4;
    float dv[4];
#pragma unroll
    for (int j = 0; j < 4; ++j) dv[j] = dinv[base + r0 + rowb + j];
#pragma unroll
    for (int ct = 0; ct < 4; ++ct)
#pragma unroll
        for (int j = 0; j < 4; ++j)
            x16[(size_t)(r0 + rowb + j) * 64 + ct * 16 + col] = f2b(acc[ct][j] * dv[j]);
}

// ---------------------------------------------------------------- mfma_first: x16 = bf16(dinv * concat(ue,ie) @ W0), fused reg loss
__global__ __launch_bounds__(256) void mfma_first(const float* __restrict__ ue,
                                                  const float* __restrict__ ie,
                                                  const float* __restrict__ W,
                                                  const float* __restrict__ dinv,
                                                  u16* __restrict__ x16,
                                                  float* __restrict__ regpart) {
    __shared__ float wsum[4];
    int lane = threadIdx.x & 63;
    short8 Bf[4][2];
    load_Bfrag(W, lane, Bf);

    int r0 = (blockIdx.x * 4 + (threadIdx.x >> 6)) * 16;
    int m  = lane & 15;
    int kb = (lane >> 4) * 8;
    int r  = r0 + m;
    const float* src = (r < N_USERS) ? (ue + (size_t)r * 64)
                                     : (ie + (size_t)(r - N_USERS) * 64);
    // A fragments: A[m][k=kb+j] (kt0), A[m][32+kb+j] (kt1); 8 f32 -> short8 each
    float sq = 0.0f;
    short8 A0, A1;
#pragma unroll
    for (int h = 0; h < 2; ++h) {
        float4 a = ((const float4*)(src + h * 32 + kb))[0];
        float4 b = ((const float4*)(src + h * 32 + kb))[1];
        short8& A = h ? A1 : A0;
        A[0] = (short)f2b(a.x); A[1] = (short)f2b(a.y);
        A[2] = (short)f2b(a.z); A[3] = (short)f2b(a.w);
        A[4] = (short)f2b(b.x); A[5] = (short)f2b(b.y);
        A[6] = (short)f2b(b.z); A[7] = (short)f2b(b.w);
        sq += a.x * a.x + a.y * a.y + a.z * a.z + a.w * a.w;
        sq += b.x * b.x + b.y * b.y + b.z * b.z + b.w * b.w;
    }
    f32x4 acc[4];
#pragma unroll
    for (int ct = 0; ct < 4; ++ct) {
        acc[ct] = (f32x4){0.f, 0.f, 0.f, 0.f};
        acc[ct] = __builtin_amdgcn_mfma_f32_16x16x32_bf16(A0, Bf[ct][0], acc[ct], 0, 0, 0);
        acc[ct] = __builtin_amdgcn_mfma_f32_16x16x32_bf16(A1, Bf[ct][1], acc[ct], 0, 0, 0);
    }
    store_tile(x16, dinv, 0, r0, lane, acc);

#pragma unroll
    for (int off = 32; off; off >>= 1) sq += __shfl_xor(sq, off, 64);
    if (lane == 0) wsum[threadIdx.x >> 6] = sq;
    __syncthreads();
    if (threadIdx.x == 0)
        regpart[blockIdx.x] = (wsum[0] + wsum[1] + wsum[2] + wsum[3]) *
                              (0.5f * 0.0001f / (float)BATCH);
}

// ---------------------------------------------------------------- fused: mfma_gemm (layer bi+1) + bpr (layer bi)
// Both roles only READ g16 (the completed layer-bi output) -> safe in one grid.
__global__ __launch_bounds__(256) void gemm_bpr(const u16* __restrict__ g16,
                                                const float* __restrict__ W,
                                                const float* __restrict__ dinv,
                                                int base,
                                                u16* __restrict__ x16,
                                                const int* __restrict__ batch,
                                                int bi,
                                                float* __restrict__ bprpart) {
    __shared__ float sp4[4];
    if (blockIdx.x < GEMM_BLOCKS) {
        int lane = threadIdx.x & 63;
        short8 Bf[4][2];
        load_Bfrag(W, lane, Bf);

        int r0 = (blockIdx.x * 4 + (threadIdx.x >> 6)) * 16;
        int m  = lane & 15;
        int kb = (lane >> 4) * 8;
        const u16* src = g16 + (size_t)(r0 + m) * 64 + kb;
        short8 A0 = *(const short8*)(src);
        short8 A1 = *(const short8*)(src + 32);
        f32x4 acc[4];
#pragma unroll
        for (int ct = 0; ct < 4; ++ct) {
            acc[ct] = (f32x4){0.f, 0.f, 0.f, 0.f};
            acc[ct] = __builtin_amdgcn_mfma_f32_16x16x32_bf16(A0, Bf[ct][0], acc[ct], 0, 0, 0);
            acc[ct] = __builtin_amdgcn_mfma_f32_16x16x32_bf16(A1, Bf[ct][1], acc[ct], 0, 0, 0);
        }
        store_tile(x16, dinv, base, r0, lane, acc);
    } else {
        int blk  = blockIdx.x - GEMM_BLOCKS;
        int b    = blk * 4 + (threadIdx.x >> 6);
        int lane = threadIdx.x & 63;
        int u  = batch[((size_t)b * NB + bi) * 3 + 0];
        int i0 = batch[((size_t)b * NB + bi) * 3 + 1];
        int i1 = batch[((size_t)b * NB + bi) * 3 + 2];
        float uf = b2f(g16[(size_t)u * 64 + lane]);
        float f0 = b2f(g16[(size_t)(N_USERS + i0) * 64 + lane]);
        float f1 = b2f(g16[(size_t)(N_USERS + i1) * 64 + lane]);
        float d  = uf * (f0 - f1);
#pragma unroll
        for (int off = 32; off; off >>= 1) d += __shfl_xor(d, off, 64);
        float sp = (d > 0.0f) ? log1pf(expf(-d)) : (-d + log1pf(expf(d)));
        if (lane == 0) sp4[threadIdx.x >> 6] = sp;
        __syncthreads();
        if (threadIdx.x == 0)
            bprpart[blk] = (sp4[0] + sp4[1] + sp4[2] + sp4[3]) * (1.0f / BATCH);
    }
}

// ---------------------------------------------------------------- agg: gather-sum + bias + l2norm + residual
// 8 nodes/wave (one per 8-lane subgroup, 8 dims/lane, 16 B row loads).
// Steady loop software-pipelined: next batch's srow indices prefetched before
// the current batch's row gathers (breaks the srow->xv dependent chain).
__global__ __launch_bounds__(256) void agg_kernel(const int* __restrict__ srow,
                                                  const int* __restrict__ startv,
                                                  const float* __restrict__ dinv,
                                                  const int4* __restrict__ xv,
                                                  const float4* __restrict__ reslo,
                                                  const float4* __restrict__ reshi,
                                                  const int4* __restrict__ res16,
                                                  int resf32,
                                                  int4* __restrict__ g16out,
                                                  const float* __restrict__ bias,
                                                  int base /* bi*N_NODES */) {
    int lane = threadIdx.x & 63;
    int li   = lane & 7;                                        // dim chunk (8 dims, 16 B)
    int c = (blockIdx.x * 4 + (threadIdx.x >> 6)) * 8 + (lane >> 3);  // < 200000 exact

    int   s   = startv[base + c];
    int   end = startv[base + c + 1];
    float dc  = dinv[base + c];

    float acc[8];
#pragma unroll
    for (int d = 0; d < 8; ++d) acc[d] = 0.0f;

    int e = s;
    // steady state: full 8-edge batches, srow prefetched one batch ahead
    if (e + 8 <= end) {
        int r[8];
#pragma unroll
        for (int j = 0; j < 8; ++j) r[j] = srow[e + j];
        for (;;) {
            int  e2    = e + 8;
            bool have2 = (e2 + 8 <= end);
            int  rn[8];
            if (have2) {
#pragma unroll
                for (int j = 0; j < 8; ++j) rn[j] = srow[e2 + j];
            }
#pragma unroll
            for (int jj = 0; jj < 8; ++jj) {
                int4 w = xv[(size_t)r[jj] * 8 + li];
                acc[0] += __uint_as_float(((unsigned)w.x) << 16);
                acc[1] += __uint_as_float(((unsigned)w.x) & 0xFFFF0000u);
                acc[2] += __uint_as_float(((unsigned)w.y) << 16);
                acc[3] += __uint_as_float(((unsigned)w.y) & 0xFFFF0000u);
                acc[4] += __uint_as_float(((unsigned)w.z) << 16);
                acc[5] += __uint_as_float(((unsigned)w.z) & 0xFFFF0000u);
                acc[6] += __uint_as_float(((unsigned)w.w) << 16);
                acc[7] += __uint_as_float(((unsigned)w.w) & 0xFFFF0000u);
            }
            e = e2;
            if (!have2) break;
#pragma unroll
            for (int j = 0; j < 8; ++j) r[j] = rn[j];
        }
    }
    // tail: masked via exact 0/1 fma multiplier
    if (e < end) {
#pragma unroll
        for (int jj = 0; jj < 8; ++jj) {
            int  ej = e + jj;
            bool ok = ej < end;
            int  ec = ok ? ej : s;
            int  r  = srow[ec];
            int4 w  = xv[(size_t)r * 8 + li];
            float m = ok ? 1.0f : 0.0f;
            acc[0] += m * __uint_as_float(((unsigned)w.x) << 16);
            acc[1] += m * __uint_as_float(((unsigned)w.x) & 0xFFFF0000u);
            acc[2] += m * __uint_as_float(((unsigned)w.y) << 16);
            acc[3] += m * __uint_as_float(((unsigned)w.y) & 0xFFFF0000u);
            acc[4] += m * __uint_as_float(((unsigned)w.z) << 16);
            acc[5] += m * __uint_as_float(((unsigned)w.z) & 0xFFFF0000u);
            acc[6] += m * __uint_as_float(((unsigned)w.w) << 16);
            acc[7] += m * __uint_as_float(((unsigned)w.w) & 0xFFFF0000u);
        }
    }

    float4 b0 = ((const float4*)bias)[li * 2];
    float4 b1 = ((const float4*)bias)[li * 2 + 1];
    float v[8];
    v[0] = acc[0] * dc + b0.x; v[1] = acc[1] * dc + b0.y;
    v[2] = acc[2] * dc + b0.z; v[3] = acc[3] * dc + b0.w;
    v[4] = acc[4] * dc + b1.x; v[5] = acc[5] * dc + b1.y;
    v[6] = acc[6] * dc + b1.z; v[7] = acc[7] * dc + b1.w;
    float sq = 0.0f;
#pragma unroll
    for (int d = 0; d < 8; ++d) sq += v[d] * v[d];
    sq += __shfl_xor(sq, 1, 64);
    sq += __shfl_xor(sq, 2, 64);
    sq += __shfl_xor(sq, 4, 64);
    float inv = 1.0f / fmaxf(sqrtf(sq), 1e-12f);

    float rv[8];
    if (resf32) {
        const float4* rsrc = (c < N_USERS)
            ? reslo + ((size_t)c * 16 + li * 2)
            : reshi + ((size_t)(c - N_USERS) * 16 + li * 2);
        float4 t0 = rsrc[0], t1 = rsrc[1];
        rv[0] = t0.x; rv[1] = t0.y; rv[2] = t0.z; rv[3] = t0.w;
        rv[4] = t1.x; rv[5] = t1.y; rv[6] = t1.z; rv[7] = t1.w;
    } else {
        int4 rw = res16[(size_t)c * 8 + li];
        rv[0] = __uint_as_float(((unsigned)rw.x) << 16);
        rv[1] = __uint_as_float(((unsigned)rw.x) & 0xFFFF0000u);
        rv[2] = __uint_as_float(((unsigned)rw.y) << 16);
        rv[3] = __uint_as_float(((unsigned)rw.y) & 0xFFFF0000u);
        rv[4] = __uint_as_float(((unsigned)rw.z) << 16);
        rv[5] = __uint_as_float(((unsigned)rw.z) & 0xFFFF0000u);
        rv[6] = __uint_as_float(((unsigned)rw.w) << 16);
        rv[7] = __uint_as_float(((unsigned)rw.w) & 0xFFFF0000u);
    }
    float o[8];
#pragma unroll
    for (int d = 0; d < 8; ++d) o[d] = rv[d] + v[d] * inv;
    int4 h;
    h.x = (int)(((unsigned)f2b(o[0])) | (((unsigned)f2b(o[1])) << 16));
    h.y = (int)(((unsigned)f2b(o[2])) | (((unsigned)f2b(o[3])) << 16));
    h.z = (int)(((unsigned)f2b(o[4])) | (((unsigned)f2b(o[5])) << 16));
    h.w = (int)(((unsigned)f2b(o[6])) | (((unsigned)f2b(o[7])) << 16));
    g16out[(size_t)c * 8 + li] = h;
}

// ---------------------------------------------------------------- BPR loss standalone (last layer) — bf16 rows
__global__ __launch_bounds__(256) void bpr_kernel(const u16* __restrict__ g16,
                                                  const int* __restrict__ batch,
                                                  int bi, float* __restrict__ bprpart) {
    __shared__ float sp4[4];
    int b    = blockIdx.x * 4 + (threadIdx.x >> 6);   // 1024 blocks, 4 samples each
    int lane = threadIdx.x & 63;
    int u  = batch[((size_t)b * NB + bi) * 3 + 0];
    int i0 = batch[((size_t)b * NB + bi) * 3 + 1];
    int i1 = batch[((size_t)b * NB + bi) * 3 + 2];
    float uf = b2f(g16[(size_t)u * 64 + lane]);
    float f0 = b2f(g16[(size_t)(N_USERS + i0) * 64 + lane]);
    float f1 = b2f(g16[(size_t)(N_USERS + i1) * 64 + lane]);
    float d  = uf * (f0 - f1);
#pragma unroll
    for (int off = 32; off; off >>= 1) d += __shfl_xor(d, off, 64);
    float sp = (d > 0.0f) ? log1pf(expf(-d)) : (-d + log1pf(expf(d)));
    if (lane == 0) sp4[threadIdx.x >> 6] = sp;
    __syncthreads();
    if (threadIdx.x == 0)
        bprpart[blockIdx.x] = (sp4[0] + sp4[1] + sp4[2] + sp4[3]) * (1.0f / BATCH);
}

// ---------------------------------------------------------------- final: reduce all partials
__global__ __launch_bounds__(256) void final_write(const float* __restrict__ parts,
                                                   float* __restrict__ out) {
    __shared__ float ws[4];
    float s = 0.0f;
    for (int i = threadIdx.x; i < NPARTS; i += 256) s += parts[i];
#pragma unroll
    for (int off = 32; off; off >>= 1) s += __shfl_xor(s, off, 64);
    if ((threadIdx.x & 63) == 0) ws[threadIdx.x >> 6] = s;
    __syncthreads();
    if (threadIdx.x == 0) out[0] = ws[0] + ws[1] + ws[2] + ws[3];
}

extern "C" void kernel_launch(void* const* d_in, const int* in_sizes, int n_in,
                              void* d_out, int out_size, void* d_ws, size_t ws_size,
                              hipStream_t stream) {
    const float* user_emb = (const float*)d_in[0];
    const float* item_emb = (const float*)d_in[1];
    const float* gcn_w    = (const float*)d_in[2];
    const float* gcn_b    = (const float*)d_in[3];
    const int*   edges    = (const int*)d_in[4];
    const int*   batch    = (const int*)d_in[5];
    float*       out      = (float*)d_out;

    const size_t NODE_F = (size_t)N_NODES * EMBED;            // 12.8M elems
    u16*     g16A   = (u16*)d_ws;                             // 25.6 MB bf16 master A
    u16*     g16B   = g16A + NODE_F;                          // 25.6 MB bf16 master B
    u16*     x16    = g16B + NODE_F;                          // 25.6 MB bf16 gemm out (dinv-prescaled)
    float*   dinv   = (float*)(x16 + NODE_F);                 //  2.4 MB
    int*     startv = (int*)(dinv + M_SEG);                   //  2.4 MB (+1 sentinel)
    int*     Hglob  = startv + M_SEG + 1;                     //  1.54 MB
    int*     bCnt   = Hglob + NBUCK * NBLKB;                  //  6 KB
    int*     bBase  = bCnt + NBUCK;                           //  6 KB
    int*     bpack  = bBase + NBUCK + 1;                      //  24 MB
    int*     srow   = bpack + NE_TOT;                         //  24 MB
    float*   parts  = (float*)(srow + NE_TOT);                //  25 KB partials
    float*   regpart = parts;                                 //  [0, 3125)
    float*   bprpart = parts + GEMM_BLOCKS;                   //  [3125, 3125+3072)

    // deterministic counting sort by destination column (must precede mfma_first:
    // the GEMMs pre-scale their output rows by dinv[src])
    scatterA<<<NB * NBLKB, 256, 0, stream>>>(edges, Hglob);
    colscan<<<(NBUCK + 3) / 4, 256, 0, stream>>>(Hglob, bCnt);
    scan_buckets<<<1, 256, 0, stream>>>(bCnt, bBase, startv);
    scatterB<<<NB * NBLKB, 256, 0, stream>>>(edges, Hglob, bCnt, bBase, bpack);
    place_kernel<<<NBUCK, 256, 0, stream>>>(bpack, bBase, startv, dinv, srow);

    // layer-0 GEMM via MFMA: reads restore-warm f32 inputs; fuses reg loss
    mfma_first<<<GEMM_BLOCKS, 256, 0, stream>>>(user_emb, item_emb,
                                                gcn_w, dinv, x16, regpart);

    // layer 0: f32 residual (original inputs), bf16 output master
    agg_kernel<<<AGG_BLOCKS, 256, 0, stream>>>(
        srow, startv, dinv, (const int4*)x16,
        (const float4*)user_emb, (const float4*)item_emb,
        (const int4*)0, 1,
        (int4*)g16A, gcn_b, 0);

    // layers 1, 2: bf16 residual chain; gemm(bi) fused with bpr(bi-1)
    u16* gcur = g16A;
    u16* gnxt = g16B;
    for (int bi = 1; bi < NB; ++bi) {
        gemm_bpr<<<GEMM_BLOCKS + BPR_BLOCKS, 256, 0, stream>>>(
            gcur, gcn_w + (size_t)bi * EMBED * EMBED, dinv, bi * N_NODES, x16,
            batch, bi - 1, bprpart + (size_t)(bi - 1) * BPR_BLOCKS);
        agg_kernel<<<AGG_BLOCKS, 256, 0, stream>>>(
            srow, startv, dinv, (const int4*)x16,
            (const float4*)0, (const float4*)0,
            (const int4*)gcur, 0,
            (int4*)gnxt, gcn_b + bi * EMBED, bi * N_NODES);
        u16* tmp = gcur; gcur = gnxt; gnxt = tmp;
    }
    // last layer's bpr (reads gcur = output of agg layer 2)
    bpr_kernel<<<BPR_BLOCKS, 256, 0, stream>>>(gcur, batch, NB - 1,
                                               bprpart + (size_t)(NB - 1) * BPR_BLOCKS);
    final_write<<<1, 256, 0, stream>>>(parts, out);
}

// Round 12
// 346.983 us; speedup vs baseline: 3.1333x; 1.0546x over previous
//
#include <hip/hip_runtime.h>

#define N_USERS  100000
#define N_ITEMS  100000
#define N_NODES  200000
#define EMBED    64
#define NB       3
#define N_EDGESC 2000000
#define NE_TOT   (NB * N_EDGESC)     // 6M
#define BATCH    4096
#define M_SEG    (NB * N_NODES)      // 600000 flat segments
#define NPART    500
#define PSIZE    400                 // N_NODES / NPART (exact)
#define NBUCK    (NB * NPART)        // 1500
#define NBLKB    256                 // edge blocks per behavior (8192 edges each)
#define EPB      8192
#define EPB4     (EPB / 4)           // 2048 int4 per block
#define NE4      (N_EDGESC / 4)      // 500000 (exact)
#define STAGE_CAP 4416               // bucket mean 4000, +6.5 sigma; LDS-staged srow
#define GEMM_BLOCKS 3125             // 3125 blocks * 4 waves * 16 rows = 200000 exact
#define AGG_BLOCKS 6250              // 6250 * 32 nodes/block = 200000 exact
#define BPR_BLOCKS 1024
#define NPARTS   (GEMM_BLOCKS + NB * 1024)   // 3125 reg + 3072 bpr
#define MSG_SCALE     32.0f          // fp8 message encode scale (avoids subnormals)
#define MSG_INV_SCALE 0.03125f

typedef unsigned short u16;
typedef unsigned char  u8;
typedef __attribute__((ext_vector_type(8))) short short8;   // 8 bf16 (4 VGPRs)
typedef __attribute__((ext_vector_type(4))) float f32x4;    // MFMA acc
typedef __attribute__((ext_vector_type(2))) float f32x2;    // cvt_pk_f32_fp8 result

__device__ __forceinline__ float b2f(u16 h) {
    return __uint_as_float(((unsigned)h) << 16);
}
__device__ __forceinline__ u16 f2b(float f) {
    unsigned u = __float_as_uint(f);
    return (u16)((u + 0x7FFF + ((u >> 16) & 1)) >> 16);   // RNE
}

// ---------------------------------------------------------------- scatterA: per-(bucket,block) hist (int4 reads)
__global__ __launch_bounds__(256) void scatterA(const int* __restrict__ edges,
                                                int* __restrict__ H) {
    __shared__ int h[NPART];
    int bi  = blockIdx.x / NBLKB;
    int blk = blockIdx.x - bi * NBLKB;
    const int4* cols4 = (const int4*)(edges + ((size_t)bi * 2 + 1) * N_EDGESC);
    for (int i = threadIdx.x; i < NPART; i += 256) h[i] = 0;
    __syncthreads();
    int b4 = blk * EPB4;
#pragma unroll 2
    for (int it = 0; it < EPB4 / 256; ++it) {
        int i4 = b4 + it * 256 + threadIdx.x;
        if (i4 < NE4) {
            int4 c = cols4[i4];
            atomicAdd(&h[c.x / PSIZE], 1);
            atomicAdd(&h[c.y / PSIZE], 1);
            atomicAdd(&h[c.z / PSIZE], 1);
            atomicAdd(&h[c.w / PSIZE], 1);
        }
    }
    __syncthreads();
    for (int i = threadIdx.x; i < NPART; i += 256)
        H[(bi * NPART + i) * NBLKB + blk] = h[i];
}

// ---------------------------------------------------------------- colscan: per-bucket exclusive scan over NBLKB=256 blocks
__global__ __launch_bounds__(256) void colscan(int* __restrict__ H,
                                               int* __restrict__ bCnt) {
    int wid = blockIdx.x * 4 + (threadIdx.x >> 6);
    if (wid >= NBUCK) return;
    int lane = threadIdx.x & 63;
    int carry = 0;
#pragma unroll
    for (int ch = 0; ch < NBLKB / 64; ++ch) {
        int i = wid * NBLKB + ch * 64 + lane;
        int v = H[i];
        int s = v;
#pragma unroll
        for (int off = 1; off < 64; off <<= 1) {
            int tt = __shfl_up(s, off, 64);
            if (lane >= off) s += tt;
        }
        H[i] = carry + s - v;
        carry += __shfl(s, 63, 64);
    }
    if (lane == 0) bCnt[wid] = carry;
}

// ---------------------------------------------------------------- scan NBUCK buckets (parallel)
__global__ __launch_bounds__(256) void scan_buckets(const int* __restrict__ bCnt,
                                                    int* __restrict__ bBase,
                                                    int* __restrict__ startv) {
    __shared__ int s[NBUCK + 1];
    __shared__ int tsum[256];
    int t = threadIdx.x;
    const int IT = (NBUCK + 255) / 256;     // 6
    int base0 = t * IT;
    int vals[IT];
    int sum = 0;
#pragma unroll
    for (int k = 0; k < IT; ++k) {
        int i = base0 + k;
        vals[k] = (i < NBUCK) ? bCnt[i] : 0;
        sum += vals[k];
    }
    tsum[t] = sum;
    __syncthreads();
    for (int off = 1; off < 256; off <<= 1) {
        int v = (t >= off) ? tsum[t - off] : 0;
        __syncthreads();
        tsum[t] += v;
        __syncthreads();
    }
    int run = tsum[t] - sum;
#pragma unroll
    for (int k = 0; k < IT; ++k) {
        int i = base0 + k;
        if (i < NBUCK) s[i] = run;
        run += vals[k];
    }
    if (t == 255) {
        s[NBUCK] = run;
        startv[M_SEG] = run;                // sentinel
    }
    __syncthreads();
    for (int i = t; i < NBUCK + 1; i += 256) bBase[i] = s[i];
}

// ---------------------------------------------------------------- scatterB: bucket placement, counts derived from scanned H.
// int4 edge reads; single pass: cursor atomics -> 32KB LDS stage -> run dump.
__global__ __launch_bounds__(256) void scatterB(const int* __restrict__ edges,
                                                const int* __restrict__ H,
                                                const int* __restrict__ bCnt,
                                                const int* __restrict__ bBase,
                                                int* __restrict__ bpack) {
    __shared__ int cur[NPART + 2];      // counts -> exclusive scan -> cursor
    __shared__ int lstart[NPART + 1];   // local exclusive scan (kept for dump)
    __shared__ int sbase[NPART];        // global base for (bucket, this block)
    __shared__ int tsum[256];
    __shared__ int stage[EPB];          // 32 KB bucket-sorted packed edges
    int bi  = blockIdx.x / NBLKB;
    int blk = blockIdx.x - bi * NBLKB;
    const int4* rows4 = (const int4*)(edges + ((size_t)bi * 2 + 0) * N_EDGESC);
    const int4* cols4 = (const int4*)(edges + ((size_t)bi * 2 + 1) * N_EDGESC);
    int t = threadIdx.x;

    // per-bucket count for this block from scanned H: cnt = H[blk+1]-H[blk]
    for (int i = t; i < NPART; i += 256) {
        int b  = bi * NPART + i;
        int hc = H[b * NBLKB + blk];
        int nx = (blk < NBLKB - 1) ? H[b * NBLKB + blk + 1] : bCnt[b];
        sbase[i] = bBase[b] + hc;
        cur[i]   = nx - hc;
    }
    if (t == 0) cur[NPART] = 0;
    __syncthreads();

    // scan cur[0..NPART] (2 items/thread covers 512 >= 501)
    int sb0 = t * 2;
    int v0 = (sb0     <= NPART) ? cur[sb0]     : 0;
    int v1 = (sb0 + 1 <= NPART) ? cur[sb0 + 1] : 0;
    int sum = v0 + v1;
    tsum[t] = sum;
    __syncthreads();
    for (int off = 1; off < 256; off <<= 1) {
        int v = (t >= off) ? tsum[t - off] : 0;
        __syncthreads();
        tsum[t] += v;
        __syncthreads();
    }
    int run = tsum[t] - sum;
    __syncthreads();
    if (sb0     <= NPART) { cur[sb0]     = run;      lstart[sb0]     = run; }
    if (sb0 + 1 <= NPART) { cur[sb0 + 1] = run + v0; lstart[sb0 + 1] = run + v0; }
    __syncthreads();

    // single main pass: int4 load (4 edges), rank via LDS cursor atomics, scatter
    int b4 = blk * EPB4;
#pragma unroll 2
    for (int it = 0; it < EPB4 / 256; ++it) {
        int i4 = b4 + it * 256 + t;
        if (i4 < NE4) {
            int4 c = cols4[i4];
            int4 r = rows4[i4];
            { int p = c.x / PSIZE; int q = atomicAdd(&cur[p], 1);
              stage[q] = ((c.x - p * PSIZE) << 18) | r.x; }
            { int p = c.y / PSIZE; int q = atomicAdd(&cur[p], 1);
              stage[q] = ((c.y - p * PSIZE) << 18) | r.y; }
            { int p = c.z / PSIZE; int q = atomicAdd(&cur[p], 1);
              stage[q] = ((c.z - p * PSIZE) << 18) | r.z; }
            { int p = c.w / PSIZE; int q = atomicAdd(&cur[p], 1);
              stage[q] = ((c.w - p * PSIZE) << 18) | r.w; }
        }
    }
    __syncthreads();

    // run-based dump: 16 lanes per bucket (runs avg ~16 words -> one 64B line)
    int grp = t >> 4;       // 16 groups of 16 lanes
    int li  = t & 15;
    for (int p = grp; p < NPART; p += 16) {
        int lb  = lstart[p];
        int len = lstart[p + 1] - lb;
        int gb  = sbase[p];
        for (int off = li; off < len; off += 16)
            bpack[gb + off] = stage[lb + off];
    }
}

// ---------------------------------------------------------------- place: one block per bucket
// hist -> scan -> startv/dinv -> rank-scatter into LDS stage -> coalesced srow dump.
__global__ __launch_bounds__(256) void place_kernel(const int* __restrict__ bpack,
                                                    const int* __restrict__ bBase,
                                                    int* __restrict__ startv,
                                                    float* __restrict__ dinv,
                                                    int* __restrict__ srow) {
    __shared__ int cnt[PSIZE + 2];
    __shared__ int tsum[256];
    __shared__ int stage[STAGE_CAP];
    int b    = blockIdx.x;
    int bi   = b / NPART;
    int part = b - bi * NPART;
    int segBase = bi * N_NODES + part * PSIZE;
    int lo = bBase[b], hiEnd = bBase[b + 1];
    int t = threadIdx.x;

    for (int i = t; i < PSIZE + 1; i += 256) cnt[i] = 0;
    __syncthreads();

    // phase 1: histogram (4-batched loads so 4 loads are in flight before atomics)
    {
        int i = lo + t;
        for (; i + 768 < hiEnd; i += 1024) {
            int a0 = bpack[i];
            int a1 = bpack[i + 256];
            int a2 = bpack[i + 512];
            int a3 = bpack[i + 768];
            atomicAdd(&cnt[a0 >> 18], 1);
            atomicAdd(&cnt[a1 >> 18], 1);
            atomicAdd(&cnt[a2 >> 18], 1);
            atomicAdd(&cnt[a3 >> 18], 1);
        }
        for (; i < hiEnd; i += 256) atomicAdd(&cnt[bpack[i] >> 18], 1);
    }
    __syncthreads();

    // scan cnt[0..PSIZE] (2 items/thread covers 512 >= 401)
    int base0 = t * 2;
    int v0 = (base0     <= PSIZE) ? cnt[base0]     : 0;
    int v1 = (base0 + 1 <= PSIZE) ? cnt[base0 + 1] : 0;
    int sum = v0 + v1;
    tsum[t] = sum;
    __syncthreads();
    for (int off = 1; off < 256; off <<= 1) {
        int v = (t >= off) ? tsum[t - off] : 0;
        __syncthreads();
        tsum[t] += v;
        __syncthreads();
    }
    int run = tsum[t] - sum;
    __syncthreads();
    if (base0     <= PSIZE) cnt[base0]     = run;
    if (base0 + 1 <= PSIZE) cnt[base0 + 1] = run + v0;
    __syncthreads();

    for (int i = t; i < PSIZE; i += 256) {
        int excl = cnt[i];
        int d    = cnt[i + 1] - excl;
        startv[segBase + i] = lo + excl;
        dinv[segBase + i]   = (d > 0) ? rsqrtf((float)d) : 0.0f;
    }
    __syncthreads();

    // phase 2: rank (LDS atomic) + stage into LDS; overflow falls back to direct write
    {
        int i = lo + t;
        for (; i + 768 < hiEnd; i += 1024) {
            int p0 = bpack[i];
            int p1 = bpack[i + 256];
            int p2 = bpack[i + 512];
            int p3 = bpack[i + 768];
            int q0 = atomicAdd(&cnt[p0 >> 18], 1);
            int q1 = atomicAdd(&cnt[p1 >> 18], 1);
            int q2 = atomicAdd(&cnt[p2 >> 18], 1);
            int q3 = atomicAdd(&cnt[p3 >> 18], 1);
            if (q0 < STAGE_CAP) stage[q0] = p0 & 0x3FFFF; else srow[lo + q0] = p0 & 0x3FFFF;
            if (q1 < STAGE_CAP) stage[q1] = p1 & 0x3FFFF; else srow[lo + q1] = p1 & 0x3FFFF;
            if (q2 < STAGE_CAP) stage[q2] = p2 & 0x3FFFF; else srow[lo + q2] = p2 & 0x3FFFF;
            if (q3 < STAGE_CAP) stage[q3] = p3 & 0x3FFFF; else srow[lo + q3] = p3 & 0x3FFFF;
        }
        for (; i < hiEnd; i += 256) {
            int pk  = bpack[i];
            int pos = atomicAdd(&cnt[pk >> 18], 1);
            if (pos < STAGE_CAP) stage[pos] = pk & 0x3FFFF; else srow[lo + pos] = pk & 0x3FFFF;
        }
    }
    __syncthreads();

    // coalesced dump
    int n = hiEnd - lo;
    int cap = (n < STAGE_CAP) ? n : STAGE_CAP;
    for (int i = t; i < cap; i += 256) srow[lo + i] = stage[i];
}

// ---------------------------------------------------------------- B-fragment loader: Bf[ct][kt] = bf16 W[k][ct*16+n]
// layout per m120: B[k = quad*8 + j][n = lane&15]
__device__ __forceinline__ void load_Bfrag(const float* __restrict__ W,
                                           int lane, short8 Bf[4][2]) {
    int n    = lane & 15;
    int kb   = (lane >> 4) * 8;
#pragma unroll
    for (int ct = 0; ct < 4; ++ct)
#pragma unroll
        for (int kt = 0; kt < 2; ++kt)
#pragma unroll
            for (int j = 0; j < 8; ++j)
                Bf[ct][kt][j] = (short)f2b(W[(kt * 32 + kb + j) * 64 + ct * 16 + n]);
}

// ---------------------------------------------------------------- MFMA store -> fp8 messages, pre-scaled by S*dinv[src]:
// x8[r] = fp8( 32 * dinv[base+r] * (X @ W)[r] )  -- agg folds 1/32 into dc.
// C/D layout: col=lane&15, row=quad*4+reg
__device__ __forceinline__ void store_tile(u8* __restrict__ x8,
                                           const float* __restrict__ dinv, int base,
                                           int r0, int lane, const f32x4 acc[4]) {
    int col  = lane & 15;
    int rowb = (lane >> 4) * 4;
    float dv[4];
#pragma unroll
    for (int j = 0; j < 4; ++j) dv[j] = dinv[base + r0 + rowb + j] * MSG_SCALE;
#pragma unroll
    for (int ct = 0; ct < 4; ++ct)
#pragma unroll
        for (int j = 0; j < 4; ++j) {
            int p = __builtin_amdgcn_cvt_pk_fp8_f32(acc[ct][j] * dv[j], 0.0f, 0, false);
            x8[(size_t)(r0 + rowb + j) * 64 + ct * 16 + col] = (u8)(p & 0xFF);
        }
}

// ---------------------------------------------------------------- mfma_first: x8 = fp8(S*dinv * concat(ue,ie) @ W0), fused reg loss
__global__ __launch_bounds__(256) void mfma_first(const float* __restrict__ ue,
                                                  const float* __restrict__ ie,
                                                  const float* __restrict__ W,
                                                  const float* __restrict__ dinv,
                                                  u8* __restrict__ x8,
                                                  float* __restrict__ regpart) {
    __shared__ float wsum[4];
    int lane = threadIdx.x & 63;
    short8 Bf[4][2];
    load_Bfrag(W, lane, Bf);

    int r0 = (blockIdx.x * 4 + (threadIdx.x >> 6)) * 16;
    int m  = lane & 15;
    int kb = (lane >> 4) * 8;
    int r  = r0 + m;
    const float* src = (r < N_USERS) ? (ue + (size_t)r * 64)
                                     : (ie + (size_t)(r - N_USERS) * 64);
    // A fragments: A[m][k=kb+j] (kt0), A[m][32+kb+j] (kt1); 8 f32 -> short8 each
    float sq = 0.0f;
    short8 A0, A1;
#pragma unroll
    for (int h = 0; h < 2; ++h) {
        float4 a = ((const float4*)(src + h * 32 + kb))[0];
        float4 b = ((const float4*)(src + h * 32 + kb))[1];
        short8& A = h ? A1 : A0;
        A[0] = (short)f2b(a.x); A[1] = (short)f2b(a.y);
        A[2] = (short)f2b(a.z); A[3] = (short)f2b(a.w);
        A[4] = (short)f2b(b.x); A[5] = (short)f2b(b.y);
        A[6] = (short)f2b(b.z); A[7] = (short)f2b(b.w);
        sq += a.x * a.x + a.y * a.y + a.z * a.z + a.w * a.w;
        sq += b.x * b.x + b.y * b.y + b.z * b.z + b.w * b.w;
    }
    f32x4 acc[4];
#pragma unroll
    for (int ct = 0; ct < 4; ++ct) {
        acc[ct] = (f32x4){0.f, 0.f, 0.f, 0.f};
        acc[ct] = __builtin_amdgcn_mfma_f32_16x16x32_bf16(A0, Bf[ct][0], acc[ct], 0, 0, 0);
        acc[ct] = __builtin_amdgcn_mfma_f32_16x16x32_bf16(A1, Bf[ct][1], acc[ct], 0, 0, 0);
    }
    store_tile(x8, dinv, 0, r0, lane, acc);

#pragma unroll
    for (int off = 32; off; off >>= 1) sq += __shfl_xor(sq, off, 64);
    if (lane == 0) wsum[threadIdx.x >> 6] = sq;
    __syncthreads();
    if (threadIdx.x == 0)
        regpart[blockIdx.x] = (wsum[0] + wsum[1] + wsum[2] + wsum[3]) *
                              (0.5f * 0.0001f / (float)BATCH);
}

// ---------------------------------------------------------------- fused: mfma_gemm (layer bi+1) + bpr (layer bi)
// Both roles only READ g16 (the completed layer-bi output) -> safe in one grid.
__global__ __launch_bounds__(256) void gemm_bpr(const u16* __restrict__ g16,
                                                const float* __restrict__ W,
                                                const float* __restrict__ dinv,
                                                int base,
                                                u8* __restrict__ x8,
                                                const int* __restrict__ batch,
                                                int bi,
                                                float* __restrict__ bprpart) {
    __shared__ float sp4[4];
    if (blockIdx.x < GEMM_BLOCKS) {
        int lane = threadIdx.x & 63;
        short8 Bf[4][2];
        load_Bfrag(W, lane, Bf);

        int r0 = (blockIdx.x * 4 + (threadIdx.x >> 6)) * 16;
        int m  = lane & 15;
        int kb = (lane >> 4) * 8;
        const u16* src = g16 + (size_t)(r0 + m) * 64 + kb;
        short8 A0 = *(const short8*)(src);
        short8 A1 = *(const short8*)(src + 32);
        f32x4 acc[4];
#pragma unroll
        for (int ct = 0; ct < 4; ++ct) {
            acc[ct] = (f32x4){0.f, 0.f, 0.f, 0.f};
            acc[ct] = __builtin_amdgcn_mfma_f32_16x16x32_bf16(A0, Bf[ct][0], acc[ct], 0, 0, 0);
            acc[ct] = __builtin_amdgcn_mfma_f32_16x16x32_bf16(A1, Bf[ct][1], acc[ct], 0, 0, 0);
        }
        store_tile(x8, dinv, base, r0, lane, acc);
    } else {
        int blk  = blockIdx.x - GEMM_BLOCKS;
        int b    = blk * 4 + (threadIdx.x >> 6);
        int lane = threadIdx.x & 63;
        int u  = batch[((size_t)b * NB + bi) * 3 + 0];
        int i0 = batch[((size_t)b * NB + bi) * 3 + 1];
        int i1 = batch[((size_t)b * NB + bi) * 3 + 2];
        float uf = b2f(g16[(size_t)u * 64 + lane]);
        float f0 = b2f(g16[(size_t)(N_USERS + i0) * 64 + lane]);
        float f1 = b2f(g16[(size_t)(N_USERS + i1) * 64 + lane]);
        float d  = uf * (f0 - f1);
#pragma unroll
        for (int off = 32; off; off >>= 1) d += __shfl_xor(d, off, 64);
        float sp = (d > 0.0f) ? log1pf(expf(-d)) : (-d + log1pf(expf(d)));
        if (lane == 0) sp4[threadIdx.x >> 6] = sp;
        __syncthreads();
        if (threadIdx.x == 0)
            bprpart[blk] = (sp4[0] + sp4[1] + sp4[2] + sp4[3]) * (1.0f / BATCH);
    }
}

// ---------------------------------------------------------------- agg: gather-sum + bias + l2norm + residual
// 8 nodes/wave (one per 8-lane subgroup, 8 dims/lane, 8 B fp8 row loads).
// Steady loop software-pipelined: next batch's srow indices prefetched before
// the current batch's row gathers. fp8 decode via v_cvt_pk_f32_fp8 (HW).
__global__ __launch_bounds__(256) void agg_kernel(const int* __restrict__ srow,
                                                  const int* __restrict__ startv,
                                                  const float* __restrict__ dinv,
                                                  const uint2* __restrict__ xv,
                                                  const float4* __restrict__ reslo,
                                                  const float4* __restrict__ reshi,
                                                  const int4* __restrict__ res16,
                                                  int resf32,
                                                  int4* __restrict__ g16out,
                                                  const float* __restrict__ bias,
                                                  int base /* bi*N_NODES */) {
    int lane = threadIdx.x & 63;
    int li   = lane & 7;                                        // dim chunk (8 dims, 8 B fp8)
    int c = (blockIdx.x * 4 + (threadIdx.x >> 6)) * 8 + (lane >> 3);  // < 200000 exact

    int   s   = startv[base + c];
    int   end = startv[base + c + 1];
    float dcS = dinv[base + c] * MSG_INV_SCALE;

    float acc[8];
#pragma unroll
    for (int d = 0; d < 8; ++d) acc[d] = 0.0f;

    int e = s;
    // steady state: full 8-edge batches, srow prefetched one batch ahead
    if (e + 8 <= end) {
        int r[8];
#pragma unroll
        for (int j = 0; j < 8; ++j) r[j] = srow[e + j];
        for (;;) {
            int  e2    = e + 8;
            bool have2 = (e2 + 8 <= end);
            int  rn[8];
            if (have2) {
#pragma unroll
                for (int j = 0; j < 8; ++j) rn[j] = srow[e2 + j];
            }
#pragma unroll
            for (int jj = 0; jj < 8; ++jj) {
                uint2 w = xv[(size_t)r[jj] * 8 + li];
                f32x2 p0 = __builtin_amdgcn_cvt_pk_f32_fp8(w.x, false);
                f32x2 p1 = __builtin_amdgcn_cvt_pk_f32_fp8(w.x, true);
                f32x2 p2 = __builtin_amdgcn_cvt_pk_f32_fp8(w.y, false);
                f32x2 p3 = __builtin_amdgcn_cvt_pk_f32_fp8(w.y, true);
                acc[0] += p0.x; acc[1] += p0.y;
                acc[2] += p1.x; acc[3] += p1.y;
                acc[4] += p2.x; acc[5] += p2.y;
                acc[6] += p3.x; acc[7] += p3.y;
            }
            e = e2;
            if (!have2) break;
#pragma unroll
            for (int j = 0; j < 8; ++j) r[j] = rn[j];
        }
    }
    // tail: masked via exact 0/1 fma multiplier
    if (e < end) {
#pragma unroll
        for (int jj = 0; jj < 8; ++jj) {
            int  ej = e + jj;
            bool ok = ej < end;
            int  ec = ok ? ej : s;
            int  r  = srow[ec];
            uint2 w = xv[(size_t)r * 8 + li];
            float m = ok ? 1.0f : 0.0f;
            f32x2 p0 = __builtin_amdgcn_cvt_pk_f32_fp8(w.x, false);
            f32x2 p1 = __builtin_amdgcn_cvt_pk_f32_fp8(w.x, true);
            f32x2 p2 = __builtin_amdgcn_cvt_pk_f32_fp8(w.y, false);
            f32x2 p3 = __builtin_amdgcn_cvt_pk_f32_fp8(w.y, true);
            acc[0] += m * p0.x; acc[1] += m * p0.y;
            acc[2] += m * p1.x; acc[3] += m * p1.y;
            acc[4] += m * p2.x; acc[5] += m * p2.y;
            acc[6] += m * p3.x; acc[7] += m * p3.y;
        }
    }

    float4 b0 = ((const float4*)bias)[li * 2];
    float4 b1 = ((const float4*)bias)[li * 2 + 1];
    float v[8];
    v[0] = acc[0] * dcS + b0.x; v[1] = acc[1] * dcS + b0.y;
    v[2] = acc[2] * dcS + b0.z; v[3] = acc[3] * dcS + b0.w;
    v[4] = acc[4] * dcS + b1.x; v[5] = acc[5] * dcS + b1.y;
    v[6] = acc[6] * dcS + b1.z; v[7] = acc[7] * dcS + b1.w;
    float sq = 0.0f;
#pragma unroll
    for (int d = 0; d < 8; ++d) sq += v[d] * v[d];
    sq += __shfl_xor(sq, 1, 64);
    sq += __shfl_xor(sq, 2, 64);
    sq += __shfl_xor(sq, 4, 64);
    float inv = 1.0f / fmaxf(sqrtf(sq), 1e-12f);

    float rv[8];
    if (resf32) {
        const float4* rsrc = (c < N_USERS)
            ? reslo + ((size_t)c * 16 + li * 2)
            : reshi + ((size_t)(c - N_USERS) * 16 + li * 2);
        float4 t0 = rsrc[0], t1 = rsrc[1];
        rv[0] = t0.x; rv[1] = t0.y; rv[2] = t0.z; rv[3] = t0.w;
        rv[4] = t1.x; rv[5] = t1.y; rv[6] = t1.z; rv[7] = t1.w;
    } else {
        int4 rw = res16[(size_t)c * 8 + li];
        rv[0] = __uint_as_float(((unsigned)rw.x) << 16);
        rv[1] = __uint_as_float(((unsigned)rw.x) & 0xFFFF0000u);
        rv[2] = __uint_as_float(((unsigned)rw.y) << 16);
        rv[3] = __uint_as_float(((unsigned)rw.y) & 0xFFFF0000u);
        rv[4] = __uint_as_float(((unsigned)rw.z) << 16);
        rv[5] = __uint_as_float(((unsigned)rw.z) & 0xFFFF0000u);
        rv[6] = __uint_as_float(((unsigned)rw.w) << 16);
        rv[7] = __uint_as_float(((unsigned)rw.w) & 0xFFFF0000u);
    }
    float o[8];
#pragma unroll
    for (int d = 0; d < 8; ++d) o[d] = rv[d] + v[d] * inv;
    int4 h;
    h.x = (int)(((unsigned)f2b(o[0])) | (((unsigned)f2b(o[1])) << 16));
    h.y = (int)(((unsigned)f2b(o[2])) | (((unsigned)f2b(o[3])) << 16));
    h.z = (int)(((unsigned)f2b(o[4])) | (((unsigned)f2b(o[5])) << 16));
    h.w = (int)(((unsigned)f2b(o[6])) | (((unsigned)f2b(o[7])) << 16));
    g16out[(size_t)c * 8 + li] = h;
}

// ---------------------------------------------------------------- BPR loss standalone (last layer) — bf16 rows
__global__ __launch_bounds__(256) void bpr_kernel(const u16* __restrict__ g16,
                                                  const int* __restrict__ batch,
                                                  int bi, float* __restrict__ bprpart) {
    __shared__ float sp4[4];
    int b    = blockIdx.x * 4 + (threadIdx.x >> 6);   // 1024 blocks, 4 samples each
    int lane = threadIdx.x & 63;
    int u  = batch[((size_t)b * NB + bi) * 3 + 0];
    int i0 = batch[((size_t)b * NB + bi) * 3 + 1];
    int i1 = batch[((size_t)b * NB + bi) * 3 + 2];
    float uf = b2f(g16[(size_t)u * 64 + lane]);
    float f0 = b2f(g16[(size_t)(N_USERS + i0) * 64 + lane]);
    float f1 = b2f(g16[(size_t)(N_USERS + i1) * 64 + lane]);
    float d  = uf * (f0 - f1);
#pragma unroll
    for (int off = 32; off; off >>= 1) d += __shfl_xor(d, off, 64);
    float sp = (d > 0.0f) ? log1pf(expf(-d)) : (-d + log1pf(expf(d)));
    if (lane == 0) sp4[threadIdx.x >> 6] = sp;
    __syncthreads();
    if (threadIdx.x == 0)
        bprpart[blockIdx.x] = (sp4[0] + sp4[1] + sp4[2] + sp4[3]) * (1.0f / BATCH);
}

// ---------------------------------------------------------------- final: reduce all partials
__global__ __launch_bounds__(256) void final_write(const float* __restrict__ parts,
                                                   float* __restrict__ out) {
    __shared__ float ws[4];
    float s = 0.0f;
    for (int i = threadIdx.x; i < NPARTS; i += 256) s += parts[i];
#pragma unroll
    for (int off = 32; off; off >>= 1) s += __shfl_xor(s, off, 64);
    if ((threadIdx.x & 63) == 0) ws[threadIdx.x >> 6] = s;
    __syncthreads();
    if (threadIdx.x == 0) out[0] = ws[0] + ws[1] + ws[2] + ws[3];
}

extern "C" void kernel_launch(void* const* d_in, const int* in_sizes, int n_in,
                              void* d_out, int out_size, void* d_ws, size_t ws_size,
                              hipStream_t stream) {
    const float* user_emb = (const float*)d_in[0];
    const float* item_emb = (const float*)d_in[1];
    const float* gcn_w    = (const float*)d_in[2];
    const float* gcn_b    = (const float*)d_in[3];
    const int*   edges    = (const int*)d_in[4];
    const int*   batch    = (const int*)d_in[5];
    float*       out      = (float*)d_out;

    const size_t NODE_F = (size_t)N_NODES * EMBED;            // 12.8M elems
    u16*     g16A   = (u16*)d_ws;                             // 25.6 MB bf16 master A
    u16*     g16B   = g16A + NODE_F;                          // 25.6 MB bf16 master B
    u8*      x8     = (u8*)(g16B + NODE_F);                   // 12.8 MB fp8 gemm out (S*dinv-prescaled)
    float*   dinv   = (float*)(x8 + NODE_F);                  //  2.4 MB
    int*     startv = (int*)(dinv + M_SEG);                   //  2.4 MB (+1 sentinel)
    int*     Hglob  = startv + M_SEG + 1;                     //  1.54 MB
    int*     bCnt   = Hglob + NBUCK * NBLKB;                  //  6 KB
    int*     bBase  = bCnt + NBUCK;                           //  6 KB
    int*     bpack  = bBase + NBUCK + 1;                      //  24 MB
    int*     srow   = bpack + NE_TOT;                         //  24 MB
    float*   parts  = (float*)(srow + NE_TOT);                //  25 KB partials
    float*   regpart = parts;                                 //  [0, 3125)
    float*   bprpart = parts + GEMM_BLOCKS;                   //  [3125, 3125+3072)

    // deterministic counting sort by destination column (must precede mfma_first:
    // the GEMMs pre-scale their output rows by dinv[src])
    scatterA<<<NB * NBLKB, 256, 0, stream>>>(edges, Hglob);
    colscan<<<(NBUCK + 3) / 4, 256, 0, stream>>>(Hglob, bCnt);
    scan_buckets<<<1, 256, 0, stream>>>(bCnt, bBase, startv);
    scatterB<<<NB * NBLKB, 256, 0, stream>>>(edges, Hglob, bCnt, bBase, bpack);
    place_kernel<<<NBUCK, 256, 0, stream>>>(bpack, bBase, startv, dinv, srow);

    // layer-0 GEMM via MFMA: reads restore-warm f32 inputs; fuses reg loss
    mfma_first<<<GEMM_BLOCKS, 256, 0, stream>>>(user_emb, item_emb,
                                                gcn_w, dinv, x8, regpart);

    // layer 0: f32 residual (original inputs), bf16 output master
    agg_kernel<<<AGG_BLOCKS, 256, 0, stream>>>(
        srow, startv, dinv, (const uint2*)x8,
        (const float4*)user_emb, (const float4*)item_emb,
        (const int4*)0, 1,
        (int4*)g16A, gcn_b, 0);

    // layers 1, 2: bf16 residual chain; gemm(bi) fused with bpr(bi-1)
    u16* gcur = g16A;
    u16* gnxt = g16B;
    for (int bi = 1; bi < NB; ++bi) {
        gemm_bpr<<<GEMM_BLOCKS + BPR_BLOCKS, 256, 0, stream>>>(
            gcur, gcn_w + (size_t)bi * EMBED * EMBED, dinv, bi * N_NODES, x8,
            batch, bi - 1, bprpart + (size_t)(bi - 1) * BPR_BLOCKS);
        agg_kernel<<<AGG_BLOCKS, 256, 0, stream>>>(
            srow, startv, dinv, (const uint2*)x8,
            (const float4*)0, (const float4*)0,
            (const int4*)gcur, 0,
            (int4*)gnxt, gcn_b + bi * EMBED, bi * N_NODES);
        u16* tmp = gcur; gcur = gnxt; gnxt = tmp;
    }
    // last layer's bpr (reads gcur = output of agg layer 2)
    bpr_kernel<<<BPR_BLOCKS, 256, 0, stream>>>(gcur, batch, NB - 1,
                                               bprpart + (size_t)(NB - 1) * BPR_BLOCKS);
    final_write<<<1, 256, 0, stream>>>(parts, out);
}